// Round 1
// 1387.974 us; speedup vs baseline: 1.0082x; 1.0082x over previous
//
#include <hip/hip_runtime.h>
#include <hip/hip_bf16.h>
#include <math.h>

// PSI_Full: B=8, S=4096, D=512. fp32 in/out.
// Round 7: GEMM K-loop pipelined (T3 minimum 2-phase): double-buffered LDS
// (As[2]/Bs[2], 64KB), prefetch tile t+1 issued BEFORE compute of tile t,
// ONE barrier per K-step (was 2, with zero overlap). Rationale: o1 GEMM was
// latency-bound (MfmaUtil 13.6%, HBM 6.4%, 2 blocks/CU grid-capped) — the
// vmcnt(0) drain before s_barrier now lands after the 32-MFMA phase instead
// of serializing with it. Scans unchanged (round-4 structure).

#define BB 8
#define SS 4096
#define DD 512
#define NCH 128
#define CHS 32        // SS / NCH
#define BSL 2         // batch per slice
#define NSL 4
#define NPROJ 2560    // 5 * DD

typedef __attribute__((ext_vector_type(8))) short short8;
typedef __attribute__((ext_vector_type(4))) float f32x4;
typedef __hip_bfloat16 bf16;

__device__ inline void load_lds16(const bf16* g, bf16* l) {
  __builtin_amdgcn_global_load_lds(
      (const __attribute__((address_space(1))) void*)g,
      (__attribute__((address_space(3))) void*)l, 16, 0, 0);
}

// ---------------------------------------------------------------------------
// bf16 MFMA GEMM: C[M,N] = act(A[M,K](lda=Alda) @ WT[N,K]^T + bias[N]) (+resid)
// act: 0 none, 1 sig, 2 sig*5, 3 gelu(exact), 9 = fused-proj table by col>>9.
// Tile 128x128, BK=64, 256 threads = 4 waves (2x2), each wave 4x4 of 16x16.
// K multiple of 64. XCD swizzle (gy==64): XCD c8 gets row band 8*c8..8*c8+7.
// Pipelined double-buffer: stage(t+1) || compute(t), 1 barrier per K-step.
// ---------------------------------------------------------------------------
__global__ __launch_bounds__(256) void gemm_mfma(
    const bf16* __restrict__ A, int Alda,
    const bf16* __restrict__ WT,            // [N][K]
    const float* __restrict__ bias,
    const float* __restrict__ resid,        // fp32 [M][N] or null
    void* __restrict__ C, int K, int N, int act, int outBf16)
{
  __shared__ bf16 As[2][8192];  // [buf][kseg 0..7][row 0..127][8]
  __shared__ bf16 Bs[2][8192];
  const int tid = threadIdx.x;
  int bx, by;
  if (gridDim.y == 64) {
    const int l = blockIdx.y * gridDim.x + blockIdx.x;
    const int c8 = l & 7, i = l >> 3;
    by = (c8 << 3) + (i & 7);     // row-block: XCD-contiguous band
    bx = i >> 3;                  // col-block
  } else { bx = blockIdx.x; by = blockIdx.y; }
  const int row0 = by << 7;
  const int col0 = bx << 7;
  const int lane = tid & 63;
  const int wv = tid >> 6;
  const int wr = (wv >> 1) << 6;
  const int wc = (wv & 1) << 6;
  const int q  = lane >> 4;
  const int mn = lane & 15;

  int eact = act;
  if (act == 9) { const int tbl[5] = {0, 1, 2, 3, 0}; eact = tbl[col0 >> 9]; }

  f32x4 acc[4][4];
#pragma unroll
  for (int i = 0; i < 4; ++i)
#pragma unroll
    for (int j = 0; j < 4; ++j) acc[i][j] = (f32x4){0.f, 0.f, 0.f, 0.f};

  const int srow = tid & 127;
  const bf16* Ag = A  + (size_t)(row0 + srow) * Alda + ((tid >> 7) << 3);
  const bf16* Bg = WT + (size_t)(col0 + srow) * K + ((tid >> 7) << 3);
  const int loff = tid * 8;

  const int nk = K >> 6;

  // prologue: stage K-tile 0 into buffer 0
#pragma unroll
  for (int i = 0; i < 4; ++i) {
    load_lds16(Ag + i * 16, &As[0][loff + i * 2048]);
    load_lds16(Bg + i * 16, &Bs[0][loff + i * 2048]);
  }
  __syncthreads();   // vmcnt(0) drain: buf0 ready

  for (int t = 0; t < nk; ++t) {
    const int cur = t & 1;
    if (t + 1 < nk) {
      const int k1 = (t + 1) << 6;
      const int nxt = cur ^ 1;
#pragma unroll
      for (int i = 0; i < 4; ++i) {
        load_lds16(Ag + k1 + i * 16, &As[nxt][loff + i * 2048]);
        load_lds16(Bg + k1 + i * 16, &Bs[nxt][loff + i * 2048]);
      }
    }
    const short8* Av = (const short8*)(As[cur]);   // index = kseg*128 + row
    const short8* Bv = (const short8*)(Bs[cur]);
#pragma unroll
    for (int j = 0; j < 2; ++j) {           // two K=32 sub-steps
      short8 af[4], bfr[4];
      const int ks = (j << 2) + q;
#pragma unroll
      for (int u = 0; u < 4; ++u) af[u]  = Av[ks * 128 + wr + u * 16 + mn];
#pragma unroll
      for (int u = 0; u < 4; ++u) bfr[u] = Bv[ks * 128 + wc + u * 16 + mn];
#pragma unroll
      for (int mt = 0; mt < 4; ++mt)
#pragma unroll
        for (int nt = 0; nt < 4; ++nt)
          acc[mt][nt] = __builtin_amdgcn_mfma_f32_16x16x32_bf16(
              af[mt], bfr[nt], acc[mt][nt], 0, 0, 0);
    }
    // one barrier per K-step: drains this step's prefetch (vmcnt0) and
    // guarantees all waves' ds_reads of buf[cur] are done before t+1
    // overwrites it.
    __syncthreads();
  }

  // C/D layout: col = lane&15, row = quad*4 + reg.
#pragma unroll
  for (int mt = 0; mt < 4; ++mt) {
#pragma unroll
    for (int nt = 0; nt < 4; ++nt) {
      const int gcol = col0 + wc + nt * 16 + mn;
      const float bcol = bias[gcol];
#pragma unroll
      for (int r = 0; r < 4; ++r) {
        const int grow = row0 + wr + mt * 16 + q * 4 + r;
        const size_t o = (size_t)grow * N + gcol;
        float v = acc[mt][nt][r] + bcol;
        if (eact == 1)      v = 1.f / (1.f + __expf(-v));
        else if (eact == 2) v = 5.f / (1.f + __expf(-v));
        else if (eact == 3) v = 0.5f * v * (1.f + erff(v * 0.70710678118654752f));
        if (resid) v += resid[o];
        if (outBf16) ((bf16*)C)[o] = __float2bfloat16(v);
        else         ((float*)C)[o] = v;
      }
    }
  }
}

// ---------------------------------------------------------------------------
__global__ __launch_bounds__(256) void wtrans(
    const float* __restrict__ W, bf16* __restrict__ WT, int K, int N)
{
  __shared__ float t[32][33];
  const int n0 = blockIdx.x << 5, k0 = blockIdx.y << 5;
  const int tx = threadIdx.x & 31, ty = threadIdx.x >> 5;
  for (int i = ty; i < 32; i += 8)
    t[i][tx] = W[(size_t)(k0 + i) * N + n0 + tx];
  __syncthreads();
  for (int i = ty; i < 32; i += 8)
    WT[(size_t)(n0 + i) * K + k0 + tx] = __float2bfloat16(t[tx][i]);
}

__global__ __launch_bounds__(256) void castbf(
    const float* __restrict__ in, bf16* __restrict__ o, int n)
{
  const int i = (blockIdx.x * 256 + threadIdx.x) * 4;
  if (i < n) {
    const float4 v = *(const float4*)(in + i);
    o[i]     = __float2bfloat16(v.x);
    o[i + 1] = __float2bfloat16(v.y);
    o[i + 2] = __float2bfloat16(v.z);
    o[i + 3] = __float2bfloat16(v.w);
  }
}

// bias concat: 5 segments of 512 -> bcat[2560]
__global__ void bconcat(const float* b0, const float* b1, const float* b2,
                        const float* b3, const float* b4, float* bcat)
{
  const int d = threadIdx.x;
  const float* src[5] = {b0, b1, b2, b3, b4};
  bcat[blockIdx.x * DD + d] = src[blockIdx.x][d];
}

// ---------------------------------------------------------------------------
// Scans (round-4 structure). proj row m: [omega|gate|mag|g1|qoff] bf16,
// stride NPROJ. phi_init in phib (bf16); running phi fp32 buffer.
// ---------------------------------------------------------------------------
__global__ __launch_bounds__(512) void scan_partialA(
    const bf16* __restrict__ proj, const float* __restrict__ iscale,
    float* __restrict__ pA)
{
  const int b = blockIdx.x >> 7;
  const int c = blockIdx.x & (NCH - 1);
  const int d = threadIdx.x;
  const float sc = fabsf(iscale[d]);
  size_t base = (((size_t)b * SS) + (size_t)c * CHS) * NPROJ + d;
  float acc = 0.f;
  for (int s = 0; s < CHS; ++s) {
    size_t idx = base + (size_t)s * NPROJ;
    acc = fmaf(__bfloat162float(proj[idx]) * __bfloat162float(proj[idx + DD]), sc, acc);
  }
  pA[((size_t)b * NCH + c) * DD + d] = acc;
}

__global__ void scan_excl(float* __restrict__ p, int batch)
{
  int t = blockIdx.x * 256 + threadIdx.x;
  if (t >= batch * DD) return;
  int g = t / DD, d = t % DD;
  size_t base = (size_t)g * NCH * DD + d;
  float run = 0.f;
  for (int c = 0; c < NCH; ++c) {
    size_t idx = base + (size_t)c * DD;
    float v = p[idx];
    p[idx] = run;
    run += v;
  }
}

__global__ __launch_bounds__(512) void scan_stageB(
    const bf16* __restrict__ proj, const bf16* __restrict__ xh,
    const bf16* __restrict__ phib, const float* __restrict__ iscale,
    float* __restrict__ phi, const float* __restrict__ pA,
    float* __restrict__ pRIM)
{
  const int b = blockIdx.x >> 7;
  const int c = blockIdx.x & (NCH - 1);
  const int d = threadIdx.x;
  const float sc = fabsf(iscale[d]);
  float accA = pA[((size_t)b * NCH + c) * DD + d];
  float aR = 0.f, aI = 0.f, aM = 0.f;
  const size_t m0 = (size_t)b * SS + (size_t)c * CHS;
  for (int s = 0; s < CHS; ++s) {
    const size_t m = m0 + s;
    const size_t pj = m * NPROJ + d;
    accA = fmaf(__bfloat162float(proj[pj]) * __bfloat162float(proj[pj + DD]), sc, accA);
    float ph = __bfloat162float(phib[m * DD + d]) + accA;
    phi[m * DD + d] = ph;
    float cp, sp;
    __sincosf(ph, &sp, &cp);
    float mg = __bfloat162float(proj[pj + 2 * DD]);
    float wc = mg * __bfloat162float(xh[m * DD + d]);
    aR = fmaf(wc, cp, aR);
    aI = fmaf(wc, sp, aI);
    aM += mg;
  }
  size_t pidx = ((size_t)b * NCH + c) * DD + d;
  const size_t stride = (size_t)BSL * NCH * DD;
  pRIM[pidx] = aR;
  pRIM[pidx + stride] = aI;
  pRIM[pidx + 2 * stride] = aM;
}

__global__ __launch_bounds__(512) void scan_final(
    const bf16* __restrict__ proj, const bf16* __restrict__ xh,
    const float* __restrict__ phi, const float* __restrict__ pRIM,
    const float* __restrict__ ln_g, const float* __restrict__ ln_b,
    bf16* __restrict__ ctxn)
{
  __shared__ float red[16];
  const int b = blockIdx.x >> 7;
  const int c = blockIdx.x & (NCH - 1);
  const int d = threadIdx.x;
  size_t pidx = ((size_t)b * NCH + c) * DD + d;
  const size_t stride = (size_t)BSL * NCH * DD;
  float aR = pRIM[pidx];
  float aI = pRIM[pidx + stride];
  float aM = pRIM[pidx + 2 * stride];
  const float g0 = ln_g[d],        e0 = ln_b[d];
  const float g1 = ln_g[DD + d],   e1 = ln_b[DD + d];
  const float g2 = ln_g[2*DD + d], e2 = ln_b[2*DD + d];
  const float g3 = ln_g[3*DD + d], e3 = ln_b[3*DD + d];
  const int lane = threadIdx.x & 63;
  const int wv = threadIdx.x >> 6;
  const size_t m0 = (size_t)b * SS + (size_t)c * CHS;
  for (int s = 0; s < CHS; ++s) {
    const size_t m = m0 + s;
    const size_t pj = m * NPROJ + d;
    float ph = phi[m * DD + d];
    float xv = __bfloat162float(xh[m * DD + d]);
    float mg = __bfloat162float(proj[pj + 2 * DD]);
    float cp, sp;
    __sincosf(ph, &sp, &cp);
    float wc = mg * xv;
    aR = fmaf(wc, cp, aR);
    aI = fmaf(wc, sp, aI);
    aM += mg;
    float inv = 1.f / sqrtf(aM + 1e-8f);
    float mr = aR * inv, mi = aI * inv;
    float pq = ph + __bfloat162float(proj[pj + 4 * DD]);
    float cq, sq;
    __sincosf(pq, &sq, &cq);
    float rr = fmaf(mr, cq, mi * sq);
    float ri = fmaf(mi, cq, -(mr * sq));
    float v0 = xv * cp, v1 = xv * sp;
    float lsum = (v0 + v1) + (rr + ri);
    float lsq  = fmaf(v0, v0, fmaf(v1, v1, fmaf(rr, rr, ri * ri)));
#pragma unroll
    for (int o = 32; o > 0; o >>= 1) {
      lsum += __shfl_down(lsum, o);
      lsq  += __shfl_down(lsq, o);
    }
    if (lane == 0) { red[wv] = lsum; red[8 + wv] = lsq; }
    __syncthreads();
    float tsum = red[0] + red[1] + red[2] + red[3] + red[4] + red[5] + red[6] + red[7];
    float tsq  = red[8] + red[9] + red[10] + red[11] + red[12] + red[13] + red[14] + red[15];
    __syncthreads();
    const float invN = 1.f / 2048.f;
    float mean = tsum * invN;
    float var  = tsq * invN - mean * mean;
    float rstd = rsqrtf(var + 1e-5f);
    size_t row = m * (4 * DD);
    ctxn[row + d]        = __float2bfloat16(fmaf((v0 - mean) * rstd, g0, e0));
    ctxn[row + DD + d]   = __float2bfloat16(fmaf((v1 - mean) * rstd, g1, e1));
    ctxn[row + 2*DD + d] = __float2bfloat16(fmaf((rr - mean) * rstd, g2, e2));
    ctxn[row + 3*DD + d] = __float2bfloat16(fmaf((ri - mean) * rstd, g3, e3));
  }
}

// ---------------------------------------------------------------------------
extern "C" void kernel_launch(void* const* d_in, const int* in_sizes, int n_in,
                              void* d_out, int out_size, void* d_ws, size_t ws_size,
                              hipStream_t stream)
{
  const float* x       = (const float*)d_in[0];
  const float* W_omega = (const float*)d_in[1];
  const float* b_omega = (const float*)d_in[2];
  const float* W_p1    = (const float*)d_in[3];
  const float* b_p1    = (const float*)d_in[4];
  const float* W_p2    = (const float*)d_in[5];
  const float* b_p2    = (const float*)d_in[6];
  const float* W_gate  = (const float*)d_in[7];
  const float* b_gate  = (const float*)d_in[8];
  const float* iscale  = (const float*)d_in[9];
  const float* W_mag   = (const float*)d_in[10];
  const float* b_mag   = (const float*)d_in[11];
  const float* W_qoff  = (const float*)d_in[12];
  const float* b_qoff  = (const float*)d_in[13];
  const float* ln_g    = (const float*)d_in[14];
  const float* ln_b    = (const float*)d_in[15];
  const float* W_o1    = (const float*)d_in[16];
  const float* b_o1    = (const float*)d_in[17];
  const float* W_o2    = (const float*)d_in[18];
  const float* b_o2    = (const float*)d_in[19];
  float* out = (float*)d_out;

  // Workspace (~119 MB). Es = BSL*SS*DD = 4.19M; Ms = 8192 rows/slice.
  const size_t Es = (size_t)BSL * SS * DD;
  const size_t Ms = (size_t)BSL * SS;
  char* p = (char*)d_ws;
  bf16* proj  = (bf16*)p; p += Ms * NPROJ * 2;            // 41.9 MB
  bf16* phib  = (bf16*)p; p += Es * 2;                    //  8.4 MB
  float* phi  = (float*)p; p += Es * 4;                   // 16.8 MB
  bf16* xh    = (bf16*)p; p += Es * 2;                    //  8.4 MB
  bf16* ctxn  = (bf16*)p; p += 4 * Es * 2;                // 33.5 MB
  float* pA   = (float*)p; p += (size_t)BSL * NCH * DD * 4;
  float* pRIM = (float*)p; p += 3 * (size_t)BSL * NCH * DD * 4;
  float* bcat = (float*)p; p += NPROJ * 4;
  bf16* WTcat = (bf16*)p; p += (size_t)NPROJ * DD * 2;    //  2.6 MB
  bf16* WTp2  = (bf16*)p; p += (size_t)DD * DD * 2;
  bf16* WTo1  = (bf16*)p; p += (size_t)2048 * 1024 * 2;   //  4.2 MB
  bf16* WTo2  = (bf16*)p; p += (size_t)1024 * 512 * 2;
  bf16* hh    = proj;                                     // [8192,1024] overlay

  dim3 tb(256);
  const size_t WD = (size_t)DD * DD;
  wtrans<<<dim3(16, 16), tb, 0, stream>>>(W_omega, WTcat,          DD, DD);
  wtrans<<<dim3(16, 16), tb, 0, stream>>>(W_gate,  WTcat + WD,     DD, DD);
  wtrans<<<dim3(16, 16), tb, 0, stream>>>(W_mag,   WTcat + 2 * WD, DD, DD);
  wtrans<<<dim3(16, 16), tb, 0, stream>>>(W_p1,    WTcat + 3 * WD, DD, DD);
  wtrans<<<dim3(16, 16), tb, 0, stream>>>(W_qoff,  WTcat + 4 * WD, DD, DD);
  wtrans<<<dim3(16, 16), tb, 0, stream>>>(W_p2,    WTp2, DD, DD);
  wtrans<<<dim3(32, 64), tb, 0, stream>>>(W_o1,    WTo1, 4 * DD, 2 * DD);
  wtrans<<<dim3(16, 32), tb, 0, stream>>>(W_o2,    WTo2, 2 * DD, DD);
  bconcat<<<5, DD, 0, stream>>>(b_omega, b_gate, b_mag, b_p1, b_qoff, bcat);

  const dim3 gP(NPROJ / 128, Ms / 128);        // (20,64)
  const dim3 gD(DD / 128, Ms / 128);           // (4,64)
  const dim3 gO1((2 * DD) / 128, Ms / 128);    // (8,64)

  for (int sl = 0; sl < NSL; ++sl) {
    const float* xs = x + sl * Es;
    float* outs = out + sl * Es;
    castbf<<<(int)(Es / 1024), tb, 0, stream>>>(xs, xh, (int)Es);
    // fused projections + p2
    gemm_mfma<<<gP, tb, 0, stream>>>(xh, DD, WTcat, bcat, nullptr, proj, DD, NPROJ, 9, 1);
    gemm_mfma<<<gD, tb, 0, stream>>>(proj + 3 * DD, NPROJ, WTp2, b_p2, nullptr, phib, DD, DD, 0, 1);
    // scans
    scan_partialA<<<BSL * NCH, 512, 0, stream>>>(proj, iscale, pA);
    scan_excl<<<(BSL * DD + 255) / 256, 256, 0, stream>>>(pA, BSL);
    scan_stageB<<<BSL * NCH, 512, 0, stream>>>(proj, xh, phib, iscale, phi, pA, pRIM);
    scan_excl<<<(3 * BSL * DD + 255) / 256, 256, 0, stream>>>(pRIM, 3 * BSL);
    scan_final<<<BSL * NCH, 512, 0, stream>>>(proj, xh, phi, pRIM, ln_g, ln_b, ctxn);
    // output MLP
    gemm_mfma<<<gO1, tb, 0, stream>>>(ctxn, 4 * DD, WTo1, b_o1, nullptr, hh, 4 * DD, 2 * DD, 3, 1);
    gemm_mfma<<<gD, tb, 0, stream>>>(hh, 2 * DD, WTo2, b_o2, xs, outs, 2 * DD, DD, 0, 0);
  }
}

// Round 2
// 1380.311 us; speedup vs baseline: 1.0138x; 1.0056x over previous
//
#include <hip/hip_runtime.h>
#include <hip/hip_bf16.h>
#include <math.h>

// PSI_Full: B=8, S=4096, D=512. fp32 in/out.
// Round 8: T4 counted-vmcnt pipeline. Round-7's __syncthreads() drained
// vmcnt(0) every K-step, killing the prefetch (o1 flat at 99us, MfmaUtil
// 13.4%). Now: raw s_barrier + per-wave `s_waitcnt vmcnt(8)` (8 loads/stage;
// tiles t,t+1 in flight = 16 outstanding -> vmcnt(8) retires exactly tile t).
// Stage for t+2 issued after the post-compute barrier, flies ~2 iterations.
// vmcnt(0) only on the last iteration. sched_barrier(0) fences around raw
// barriers (rule #18), setprio(1) around compute (T5). Scans unchanged.

#define BB 8
#define SS 4096
#define DD 512
#define NCH 128
#define CHS 32        // SS / NCH
#define BSL 2         // batch per slice
#define NSL 4
#define NPROJ 2560    // 5 * DD

typedef __attribute__((ext_vector_type(8))) short short8;
typedef __attribute__((ext_vector_type(4))) float f32x4;
typedef __hip_bfloat16 bf16;

__device__ inline void load_lds16(const bf16* g, bf16* l) {
  __builtin_amdgcn_global_load_lds(
      (const __attribute__((address_space(1))) void*)g,
      (__attribute__((address_space(3))) void*)l, 16, 0, 0);
}

// ---------------------------------------------------------------------------
// bf16 MFMA GEMM: C[M,N] = act(A[M,K](lda=Alda) @ WT[N,K]^T + bias[N]) (+resid)
// act: 0 none, 1 sig, 2 sig*5, 3 gelu(exact), 9 = fused-proj table by col>>9.
// Tile 128x128, BK=64, 256 threads = 4 waves (2x2), each wave 4x4 of 16x16.
// K multiple of 64. XCD swizzle (gy==64): XCD c8 gets row band 8*c8..8*c8+7.
// Counted-vmcnt double-buffer: loads for tile t+2 in flight across 2 iters.
// ---------------------------------------------------------------------------
__global__ __launch_bounds__(256) void gemm_mfma(
    const bf16* __restrict__ A, int Alda,
    const bf16* __restrict__ WT,            // [N][K]
    const float* __restrict__ bias,
    const float* __restrict__ resid,        // fp32 [M][N] or null
    void* __restrict__ C, int K, int N, int act, int outBf16)
{
  __shared__ bf16 As[2][8192];  // [buf][kseg 0..7][row 0..127][8]
  __shared__ bf16 Bs[2][8192];
  const int tid = threadIdx.x;
  int bx, by;
  if (gridDim.y == 64) {
    const int l = blockIdx.y * gridDim.x + blockIdx.x;
    const int c8 = l & 7, i = l >> 3;
    by = (c8 << 3) + (i & 7);     // row-block: XCD-contiguous band
    bx = i >> 3;                  // col-block
  } else { bx = blockIdx.x; by = blockIdx.y; }
  const int row0 = by << 7;
  const int col0 = bx << 7;
  const int lane = tid & 63;
  const int wv = tid >> 6;
  const int wr = (wv >> 1) << 6;
  const int wc = (wv & 1) << 6;
  const int q  = lane >> 4;
  const int mn = lane & 15;

  int eact = act;
  if (act == 9) { const int tbl[5] = {0, 1, 2, 3, 0}; eact = tbl[col0 >> 9]; }

  f32x4 acc[4][4];
#pragma unroll
  for (int i = 0; i < 4; ++i)
#pragma unroll
    for (int j = 0; j < 4; ++j) acc[i][j] = (f32x4){0.f, 0.f, 0.f, 0.f};

  const int srow = tid & 127;
  const bf16* Ag = A  + (size_t)(row0 + srow) * Alda + ((tid >> 7) << 3);
  const bf16* Bg = WT + (size_t)(col0 + srow) * K + ((tid >> 7) << 3);
  const int loff = tid * 8;

  const int nk = K >> 6;

  // prologue: stage tiles 0 and 1 (16 loads in flight per wave)
#pragma unroll
  for (int i = 0; i < 4; ++i) {
    load_lds16(Ag + i * 16, &As[0][loff + i * 2048]);
    load_lds16(Bg + i * 16, &Bs[0][loff + i * 2048]);
  }
  if (nk > 1) {
#pragma unroll
    for (int i = 0; i < 4; ++i) {
      load_lds16(Ag + 64 + i * 16, &As[1][loff + i * 2048]);
      load_lds16(Bg + 64 + i * 16, &Bs[1][loff + i * 2048]);
    }
  }

  for (int t = 0; t < nk; ++t) {
    const int cur = t & 1;
    // Retire exactly tile t's 8 loads; keep tile t+1's in flight.
    if (t + 1 < nk) asm volatile("s_waitcnt vmcnt(8)" ::: "memory");
    else            asm volatile("s_waitcnt vmcnt(0)" ::: "memory");
    __builtin_amdgcn_sched_barrier(0);
    __builtin_amdgcn_s_barrier();        // buf[cur] fully staged (all waves)
    __builtin_amdgcn_sched_barrier(0);

    const short8* Av = (const short8*)(As[cur]);   // index = kseg*128 + row
    const short8* Bv = (const short8*)(Bs[cur]);
    __builtin_amdgcn_s_setprio(1);
#pragma unroll
    for (int j = 0; j < 2; ++j) {           // two K=32 sub-steps
      short8 af[4], bfr[4];
      const int ks = (j << 2) + q;
#pragma unroll
      for (int u = 0; u < 4; ++u) af[u]  = Av[ks * 128 + wr + u * 16 + mn];
#pragma unroll
      for (int u = 0; u < 4; ++u) bfr[u] = Bv[ks * 128 + wc + u * 16 + mn];
#pragma unroll
      for (int mt = 0; mt < 4; ++mt)
#pragma unroll
        for (int nt = 0; nt < 4; ++nt)
          acc[mt][nt] = __builtin_amdgcn_mfma_f32_16x16x32_bf16(
              af[mt], bfr[nt], acc[mt][nt], 0, 0, 0);
    }
    __builtin_amdgcn_s_setprio(0);
    __builtin_amdgcn_sched_barrier(0);
    __builtin_amdgcn_s_barrier();        // all waves done reading buf[cur]
    __builtin_amdgcn_sched_barrier(0);

    if (t + 2 < nk) {                    // overwrite buf[cur] with tile t+2
      const int k2 = (t + 2) << 6;
#pragma unroll
      for (int i = 0; i < 4; ++i) {
        load_lds16(Ag + k2 + i * 16, &As[cur][loff + i * 2048]);
        load_lds16(Bg + k2 + i * 16, &Bs[cur][loff + i * 2048]);
      }
    }
  }

  // C/D layout: col = lane&15, row = quad*4 + reg.
#pragma unroll
  for (int mt = 0; mt < 4; ++mt) {
#pragma unroll
    for (int nt = 0; nt < 4; ++nt) {
      const int gcol = col0 + wc + nt * 16 + mn;
      const float bcol = bias[gcol];
#pragma unroll
      for (int r = 0; r < 4; ++r) {
        const int grow = row0 + wr + mt * 16 + q * 4 + r;
        const size_t o = (size_t)grow * N + gcol;
        float v = acc[mt][nt][r] + bcol;
        if (eact == 1)      v = 1.f / (1.f + __expf(-v));
        else if (eact == 2) v = 5.f / (1.f + __expf(-v));
        else if (eact == 3) v = 0.5f * v * (1.f + erff(v * 0.70710678118654752f));
        if (resid) v += resid[o];
        if (outBf16) ((bf16*)C)[o] = __float2bfloat16(v);
        else         ((float*)C)[o] = v;
      }
    }
  }
}

// ---------------------------------------------------------------------------
__global__ __launch_bounds__(256) void wtrans(
    const float* __restrict__ W, bf16* __restrict__ WT, int K, int N)
{
  __shared__ float t[32][33];
  const int n0 = blockIdx.x << 5, k0 = blockIdx.y << 5;
  const int tx = threadIdx.x & 31, ty = threadIdx.x >> 5;
  for (int i = ty; i < 32; i += 8)
    t[i][tx] = W[(size_t)(k0 + i) * N + n0 + tx];
  __syncthreads();
  for (int i = ty; i < 32; i += 8)
    WT[(size_t)(n0 + i) * K + k0 + tx] = __float2bfloat16(t[tx][i]);
}

__global__ __launch_bounds__(256) void castbf(
    const float* __restrict__ in, bf16* __restrict__ o, int n)
{
  const int i = (blockIdx.x * 256 + threadIdx.x) * 4;
  if (i < n) {
    const float4 v = *(const float4*)(in + i);
    o[i]     = __float2bfloat16(v.x);
    o[i + 1] = __float2bfloat16(v.y);
    o[i + 2] = __float2bfloat16(v.z);
    o[i + 3] = __float2bfloat16(v.w);
  }
}

// bias concat: 5 segments of 512 -> bcat[2560]
__global__ void bconcat(const float* b0, const float* b1, const float* b2,
                        const float* b3, const float* b4, float* bcat)
{
  const int d = threadIdx.x;
  const float* src[5] = {b0, b1, b2, b3, b4};
  bcat[blockIdx.x * DD + d] = src[blockIdx.x][d];
}

// ---------------------------------------------------------------------------
// Scans (round-4 structure). proj row m: [omega|gate|mag|g1|qoff] bf16,
// stride NPROJ. phi_init in phib (bf16); running phi fp32 buffer.
// ---------------------------------------------------------------------------
__global__ __launch_bounds__(512) void scan_partialA(
    const bf16* __restrict__ proj, const float* __restrict__ iscale,
    float* __restrict__ pA)
{
  const int b = blockIdx.x >> 7;
  const int c = blockIdx.x & (NCH - 1);
  const int d = threadIdx.x;
  const float sc = fabsf(iscale[d]);
  size_t base = (((size_t)b * SS) + (size_t)c * CHS) * NPROJ + d;
  float acc = 0.f;
  for (int s = 0; s < CHS; ++s) {
    size_t idx = base + (size_t)s * NPROJ;
    acc = fmaf(__bfloat162float(proj[idx]) * __bfloat162float(proj[idx + DD]), sc, acc);
  }
  pA[((size_t)b * NCH + c) * DD + d] = acc;
}

__global__ void scan_excl(float* __restrict__ p, int batch)
{
  int t = blockIdx.x * 256 + threadIdx.x;
  if (t >= batch * DD) return;
  int g = t / DD, d = t % DD;
  size_t base = (size_t)g * NCH * DD + d;
  float run = 0.f;
  for (int c = 0; c < NCH; ++c) {
    size_t idx = base + (size_t)c * DD;
    float v = p[idx];
    p[idx] = run;
    run += v;
  }
}

__global__ __launch_bounds__(512) void scan_stageB(
    const bf16* __restrict__ proj, const bf16* __restrict__ xh,
    const bf16* __restrict__ phib, const float* __restrict__ iscale,
    float* __restrict__ phi, const float* __restrict__ pA,
    float* __restrict__ pRIM)
{
  const int b = blockIdx.x >> 7;
  const int c = blockIdx.x & (NCH - 1);
  const int d = threadIdx.x;
  const float sc = fabsf(iscale[d]);
  float accA = pA[((size_t)b * NCH + c) * DD + d];
  float aR = 0.f, aI = 0.f, aM = 0.f;
  const size_t m0 = (size_t)b * SS + (size_t)c * CHS;
  for (int s = 0; s < CHS; ++s) {
    const size_t m = m0 + s;
    const size_t pj = m * NPROJ + d;
    accA = fmaf(__bfloat162float(proj[pj]) * __bfloat162float(proj[pj + DD]), sc, accA);
    float ph = __bfloat162float(phib[m * DD + d]) + accA;
    phi[m * DD + d] = ph;
    float cp, sp;
    __sincosf(ph, &sp, &cp);
    float mg = __bfloat162float(proj[pj + 2 * DD]);
    float wc = mg * __bfloat162float(xh[m * DD + d]);
    aR = fmaf(wc, cp, aR);
    aI = fmaf(wc, sp, aI);
    aM += mg;
  }
  size_t pidx = ((size_t)b * NCH + c) * DD + d;
  const size_t stride = (size_t)BSL * NCH * DD;
  pRIM[pidx] = aR;
  pRIM[pidx + stride] = aI;
  pRIM[pidx + 2 * stride] = aM;
}

__global__ __launch_bounds__(512) void scan_final(
    const bf16* __restrict__ proj, const bf16* __restrict__ xh,
    const float* __restrict__ phi, const float* __restrict__ pRIM,
    const float* __restrict__ ln_g, const float* __restrict__ ln_b,
    bf16* __restrict__ ctxn)
{
  __shared__ float red[16];
  const int b = blockIdx.x >> 7;
  const int c = blockIdx.x & (NCH - 1);
  const int d = threadIdx.x;
  size_t pidx = ((size_t)b * NCH + c) * DD + d;
  const size_t stride = (size_t)BSL * NCH * DD;
  float aR = pRIM[pidx];
  float aI = pRIM[pidx + stride];
  float aM = pRIM[pidx + 2 * stride];
  const float g0 = ln_g[d],        e0 = ln_b[d];
  const float g1 = ln_g[DD + d],   e1 = ln_b[DD + d];
  const float g2 = ln_g[2*DD + d], e2 = ln_b[2*DD + d];
  const float g3 = ln_g[3*DD + d], e3 = ln_b[3*DD + d];
  const int lane = threadIdx.x & 63;
  const int wv = threadIdx.x >> 6;
  const size_t m0 = (size_t)b * SS + (size_t)c * CHS;
  for (int s = 0; s < CHS; ++s) {
    const size_t m = m0 + s;
    const size_t pj = m * NPROJ + d;
    float ph = phi[m * DD + d];
    float xv = __bfloat162float(xh[m * DD + d]);
    float mg = __bfloat162float(proj[pj + 2 * DD]);
    float cp, sp;
    __sincosf(ph, &sp, &cp);
    float wc = mg * xv;
    aR = fmaf(wc, cp, aR);
    aI = fmaf(wc, sp, aI);
    aM += mg;
    float inv = 1.f / sqrtf(aM + 1e-8f);
    float mr = aR * inv, mi = aI * inv;
    float pq = ph + __bfloat162float(proj[pj + 4 * DD]);
    float cq, sq;
    __sincosf(pq, &sq, &cq);
    float rr = fmaf(mr, cq, mi * sq);
    float ri = fmaf(mi, cq, -(mr * sq));
    float v0 = xv * cp, v1 = xv * sp;
    float lsum = (v0 + v1) + (rr + ri);
    float lsq  = fmaf(v0, v0, fmaf(v1, v1, fmaf(rr, rr, ri * ri)));
#pragma unroll
    for (int o = 32; o > 0; o >>= 1) {
      lsum += __shfl_down(lsum, o);
      lsq  += __shfl_down(lsq, o);
    }
    if (lane == 0) { red[wv] = lsum; red[8 + wv] = lsq; }
    __syncthreads();
    float tsum = red[0] + red[1] + red[2] + red[3] + red[4] + red[5] + red[6] + red[7];
    float tsq  = red[8] + red[9] + red[10] + red[11] + red[12] + red[13] + red[14] + red[15];
    __syncthreads();
    const float invN = 1.f / 2048.f;
    float mean = tsum * invN;
    float var  = tsq * invN - mean * mean;
    float rstd = rsqrtf(var + 1e-5f);
    size_t row = m * (4 * DD);
    ctxn[row + d]        = __float2bfloat16(fmaf((v0 - mean) * rstd, g0, e0));
    ctxn[row + DD + d]   = __float2bfloat16(fmaf((v1 - mean) * rstd, g1, e1));
    ctxn[row + 2*DD + d] = __float2bfloat16(fmaf((rr - mean) * rstd, g2, e2));
    ctxn[row + 3*DD + d] = __float2bfloat16(fmaf((ri - mean) * rstd, g3, e3));
  }
}

// ---------------------------------------------------------------------------
extern "C" void kernel_launch(void* const* d_in, const int* in_sizes, int n_in,
                              void* d_out, int out_size, void* d_ws, size_t ws_size,
                              hipStream_t stream)
{
  const float* x       = (const float*)d_in[0];
  const float* W_omega = (const float*)d_in[1];
  const float* b_omega = (const float*)d_in[2];
  const float* W_p1    = (const float*)d_in[3];
  const float* b_p1    = (const float*)d_in[4];
  const float* W_p2    = (const float*)d_in[5];
  const float* b_p2    = (const float*)d_in[6];
  const float* W_gate  = (const float*)d_in[7];
  const float* b_gate  = (const float*)d_in[8];
  const float* iscale  = (const float*)d_in[9];
  const float* W_mag   = (const float*)d_in[10];
  const float* b_mag   = (const float*)d_in[11];
  const float* W_qoff  = (const float*)d_in[12];
  const float* b_qoff  = (const float*)d_in[13];
  const float* ln_g    = (const float*)d_in[14];
  const float* ln_b    = (const float*)d_in[15];
  const float* W_o1    = (const float*)d_in[16];
  const float* b_o1    = (const float*)d_in[17];
  const float* W_o2    = (const float*)d_in[18];
  const float* b_o2    = (const float*)d_in[19];
  float* out = (float*)d_out;

  // Workspace (~119 MB). Es = BSL*SS*DD = 4.19M; Ms = 8192 rows/slice.
  const size_t Es = (size_t)BSL * SS * DD;
  const size_t Ms = (size_t)BSL * SS;
  char* p = (char*)d_ws;
  bf16* proj  = (bf16*)p; p += Ms * NPROJ * 2;            // 41.9 MB
  bf16* phib  = (bf16*)p; p += Es * 2;                    //  8.4 MB
  float* phi  = (float*)p; p += Es * 4;                   // 16.8 MB
  bf16* xh    = (bf16*)p; p += Es * 2;                    //  8.4 MB
  bf16* ctxn  = (bf16*)p; p += 4 * Es * 2;                // 33.5 MB
  float* pA   = (float*)p; p += (size_t)BSL * NCH * DD * 4;
  float* pRIM = (float*)p; p += 3 * (size_t)BSL * NCH * DD * 4;
  float* bcat = (float*)p; p += NPROJ * 4;
  bf16* WTcat = (bf16*)p; p += (size_t)NPROJ * DD * 2;    //  2.6 MB
  bf16* WTp2  = (bf16*)p; p += (size_t)DD * DD * 2;
  bf16* WTo1  = (bf16*)p; p += (size_t)2048 * 1024 * 2;   //  4.2 MB
  bf16* WTo2  = (bf16*)p; p += (size_t)1024 * 512 * 2;
  bf16* hh    = proj;                                     // [8192,1024] overlay

  dim3 tb(256);
  const size_t WD = (size_t)DD * DD;
  wtrans<<<dim3(16, 16), tb, 0, stream>>>(W_omega, WTcat,          DD, DD);
  wtrans<<<dim3(16, 16), tb, 0, stream>>>(W_gate,  WTcat + WD,     DD, DD);
  wtrans<<<dim3(16, 16), tb, 0, stream>>>(W_mag,   WTcat + 2 * WD, DD, DD);
  wtrans<<<dim3(16, 16), tb, 0, stream>>>(W_p1,    WTcat + 3 * WD, DD, DD);
  wtrans<<<dim3(16, 16), tb, 0, stream>>>(W_qoff,  WTcat + 4 * WD, DD, DD);
  wtrans<<<dim3(16, 16), tb, 0, stream>>>(W_p2,    WTp2, DD, DD);
  wtrans<<<dim3(32, 64), tb, 0, stream>>>(W_o1,    WTo1, 4 * DD, 2 * DD);
  wtrans<<<dim3(16, 32), tb, 0, stream>>>(W_o2,    WTo2, 2 * DD, DD);
  bconcat<<<5, DD, 0, stream>>>(b_omega, b_gate, b_mag, b_p1, b_qoff, bcat);

  const dim3 gP(NPROJ / 128, Ms / 128);        // (20,64)
  const dim3 gD(DD / 128, Ms / 128);           // (4,64)
  const dim3 gO1((2 * DD) / 128, Ms / 128);    // (8,64)

  for (int sl = 0; sl < NSL; ++sl) {
    const float* xs = x + sl * Es;
    float* outs = out + sl * Es;
    castbf<<<(int)(Es / 1024), tb, 0, stream>>>(xs, xh, (int)Es);
    // fused projections + p2
    gemm_mfma<<<gP, tb, 0, stream>>>(xh, DD, WTcat, bcat, nullptr, proj, DD, NPROJ, 9, 1);
    gemm_mfma<<<gD, tb, 0, stream>>>(proj + 3 * DD, NPROJ, WTp2, b_p2, nullptr, phib, DD, DD, 0, 1);
    // scans
    scan_partialA<<<BSL * NCH, 512, 0, stream>>>(proj, iscale, pA);
    scan_excl<<<(BSL * DD + 255) / 256, 256, 0, stream>>>(pA, BSL);
    scan_stageB<<<BSL * NCH, 512, 0, stream>>>(proj, xh, phib, iscale, phi, pA, pRIM);
    scan_excl<<<(3 * BSL * DD + 255) / 256, 256, 0, stream>>>(pRIM, 3 * BSL);
    scan_final<<<BSL * NCH, 512, 0, stream>>>(proj, xh, phi, pRIM, ln_g, ln_b, ctxn);
    // output MLP
    gemm_mfma<<<gO1, tb, 0, stream>>>(ctxn, 4 * DD, WTo1, b_o1, nullptr, hh, 4 * DD, 2 * DD, 3, 1);
    gemm_mfma<<<gD, tb, 0, stream>>>(hh, 2 * DD, WTo2, b_o2, xs, outs, 2 * DD, DD, 0, 0);
  }
}

// Round 3
// 1342.860 us; speedup vs baseline: 1.0421x; 1.0279x over previous
//
#include <hip/hip_runtime.h>
#include <hip/hip_bf16.h>
#include <math.h>

// PSI_Full: B=8, S=4096, D=512. fp32 in/out.
// Round 9: LDS-DMA alias fix. Rounds 7/8 both null because global_load_lds
// writes LDS, and ds_read of As[cur] from the SAME array as the in-flight
// DMA into As[nxt] forces SIInsertWaitcnts to emit vmcnt(0) before the
// ds_reads (can't disambiguate) — draining the prefetch every K-step.
// Now: 4 DISTINCT __shared__ arrays (As0/Bs0/As1/Bs1) + 2x-unrolled K-loop
// with statically-named buffers, so alias analysis proves the compute-phase
// ds_reads don't touch the in-flight DMA destination. Explicit vmcnt(8)
// before each s_barrier keeps the cross-wave buffer-ready protocol.
// nk even >=4 at every call site (8/8/32/16). Scans unchanged.

#define BB 8
#define SS 4096
#define DD 512
#define NCH 128
#define CHS 32        // SS / NCH
#define BSL 2         // batch per slice
#define NSL 4
#define NPROJ 2560    // 5 * DD

typedef __attribute__((ext_vector_type(8))) short short8;
typedef __attribute__((ext_vector_type(4))) float f32x4;
typedef __hip_bfloat16 bf16;

__device__ inline void load_lds16(const bf16* g, bf16* l) {
  __builtin_amdgcn_global_load_lds(
      (const __attribute__((address_space(1))) void*)g,
      (__attribute__((address_space(3))) void*)l, 16, 0, 0);
}

// ---------------------------------------------------------------------------
// bf16 MFMA GEMM: C[M,N] = act(A[M,K](lda=Alda) @ WT[N,K]^T + bias[N]) (+resid)
// act: 0 none, 1 sig, 2 sig*5, 3 gelu(exact), 9 = fused-proj table by col>>9.
// Tile 128x128, BK=64, 256 threads = 4 waves (2x2), each wave 4x4 of 16x16.
// K multiple of 128 (nk even >= 4). XCD swizzle (gy==64).
// ---------------------------------------------------------------------------
__global__ __launch_bounds__(256) void gemm_mfma(
    const bf16* __restrict__ A, int Alda,
    const bf16* __restrict__ WT,            // [N][K]
    const float* __restrict__ bias,
    const float* __restrict__ resid,        // fp32 [M][N] or null
    void* __restrict__ C, int K, int N, int act, int outBf16)
{
  __shared__ bf16 As0[8192];  // [kseg 0..7][row 0..127][8]
  __shared__ bf16 Bs0[8192];
  __shared__ bf16 As1[8192];
  __shared__ bf16 Bs1[8192];
  const int tid = threadIdx.x;
  int bx, by;
  if (gridDim.y == 64) {
    const int l = blockIdx.y * gridDim.x + blockIdx.x;
    const int c8 = l & 7, i = l >> 3;
    by = (c8 << 3) + (i & 7);     // row-block: XCD-contiguous band
    bx = i >> 3;                  // col-block
  } else { bx = blockIdx.x; by = blockIdx.y; }
  const int row0 = by << 7;
  const int col0 = bx << 7;
  const int lane = tid & 63;
  const int wv = tid >> 6;
  const int wr = (wv >> 1) << 6;
  const int wc = (wv & 1) << 6;
  const int q  = lane >> 4;
  const int mn = lane & 15;

  int eact = act;
  if (act == 9) { const int tbl[5] = {0, 1, 2, 3, 0}; eact = tbl[col0 >> 9]; }

  f32x4 acc[4][4];
#pragma unroll
  for (int i = 0; i < 4; ++i)
#pragma unroll
    for (int j = 0; j < 4; ++j) acc[i][j] = (f32x4){0.f, 0.f, 0.f, 0.f};

  const int srow = tid & 127;
  const bf16* Ag = A  + (size_t)(row0 + srow) * Alda + ((tid >> 7) << 3);
  const bf16* Bg = WT + (size_t)(col0 + srow) * K + ((tid >> 7) << 3);
  const int loff = tid * 8;

  const int nk = K >> 6;   // even, >= 4 at every call site

#define STAGE(kk, AsX, BsX)                                    \
  _Pragma("unroll")                                            \
  for (int i = 0; i < 4; ++i) {                                \
    load_lds16(Ag + (kk) + i * 16, &AsX[loff + i * 2048]);     \
    load_lds16(Bg + (kk) + i * 16, &BsX[loff + i * 2048]);     \
  }

#define COMPUTE(AsX, BsX)                                      \
  do {                                                         \
    const short8* Av = (const short8*)AsX;                     \
    const short8* Bv = (const short8*)BsX;                     \
    _Pragma("unroll")                                          \
    for (int j = 0; j < 2; ++j) {                              \
      short8 af[4], bfr[4];                                    \
      const int ks = (j << 2) + q;                             \
      _Pragma("unroll")                                        \
      for (int u = 0; u < 4; ++u) af[u]  = Av[ks * 128 + wr + u * 16 + mn]; \
      _Pragma("unroll")                                        \
      for (int u = 0; u < 4; ++u) bfr[u] = Bv[ks * 128 + wc + u * 16 + mn]; \
      _Pragma("unroll")                                        \
      for (int mt = 0; mt < 4; ++mt)                           \
        _Pragma("unroll")                                      \
        for (int nt = 0; nt < 4; ++nt)                         \
          acc[mt][nt] = __builtin_amdgcn_mfma_f32_16x16x32_bf16( \
              af[mt], bfr[nt], acc[mt][nt], 0, 0, 0);          \
    }                                                          \
  } while (0)

#define WAITV(n)                                               \
  asm volatile("s_waitcnt vmcnt(" #n ")" ::: "memory");        \
  __builtin_amdgcn_sched_barrier(0)

#define BARRIER()                                              \
  __builtin_amdgcn_sched_barrier(0);                           \
  __builtin_amdgcn_s_barrier();                                \
  __builtin_amdgcn_sched_barrier(0)

  // prologue: stage tiles 0 (buf0) and 1 (buf1); 16 loads in flight/wave
  STAGE(0, As0, Bs0);
  STAGE(64, As1, Bs1);

  int k2 = 128;
  for (int t = 0; t < nk - 2; t += 2) {
    WAITV(8);              // retire tile t's 8 loads (buf0); keep t+1 flying
    BARRIER();             // buf0 ready on all waves
    COMPUTE(As0, Bs0);     // no compiler vmcnt: outstanding DMAs hit As1/Bs1
    BARRIER();             // all waves done reading buf0
    STAGE(k2, As0, Bs0);   // tile t+2 -> buf0 (flies through next compute)
    k2 += 64;
    WAITV(8);              // retire tile t+1 (buf1); keep t+2 flying
    BARRIER();
    COMPUTE(As1, Bs1);
    BARRIER();
    STAGE(k2, As1, Bs1);   // tile t+3 -> buf1
    k2 += 64;
  }
  // epilogue: tiles nk-2 (buf0) and nk-1 (buf1) still in flight
  WAITV(8);
  BARRIER();
  COMPUTE(As0, Bs0);
  WAITV(0);
  BARRIER();
  COMPUTE(As1, Bs1);

#undef STAGE
#undef COMPUTE
#undef WAITV
#undef BARRIER

  // C/D layout: col = lane&15, row = quad*4 + reg.
#pragma unroll
  for (int mt = 0; mt < 4; ++mt) {
#pragma unroll
    for (int nt = 0; nt < 4; ++nt) {
      const int gcol = col0 + wc + nt * 16 + mn;
      const float bcol = bias[gcol];
#pragma unroll
      for (int r = 0; r < 4; ++r) {
        const int grow = row0 + wr + mt * 16 + q * 4 + r;
        const size_t o = (size_t)grow * N + gcol;
        float v = acc[mt][nt][r] + bcol;
        if (eact == 1)      v = 1.f / (1.f + __expf(-v));
        else if (eact == 2) v = 5.f / (1.f + __expf(-v));
        else if (eact == 3) v = 0.5f * v * (1.f + erff(v * 0.70710678118654752f));
        if (resid) v += resid[o];
        if (outBf16) ((bf16*)C)[o] = __float2bfloat16(v);
        else         ((float*)C)[o] = v;
      }
    }
  }
}

// ---------------------------------------------------------------------------
__global__ __launch_bounds__(256) void wtrans(
    const float* __restrict__ W, bf16* __restrict__ WT, int K, int N)
{
  __shared__ float t[32][33];
  const int n0 = blockIdx.x << 5, k0 = blockIdx.y << 5;
  const int tx = threadIdx.x & 31, ty = threadIdx.x >> 5;
  for (int i = ty; i < 32; i += 8)
    t[i][tx] = W[(size_t)(k0 + i) * N + n0 + tx];
  __syncthreads();
  for (int i = ty; i < 32; i += 8)
    WT[(size_t)(n0 + i) * K + k0 + tx] = __float2bfloat16(t[tx][i]);
}

__global__ __launch_bounds__(256) void castbf(
    const float* __restrict__ in, bf16* __restrict__ o, int n)
{
  const int i = (blockIdx.x * 256 + threadIdx.x) * 4;
  if (i < n) {
    const float4 v = *(const float4*)(in + i);
    o[i]     = __float2bfloat16(v.x);
    o[i + 1] = __float2bfloat16(v.y);
    o[i + 2] = __float2bfloat16(v.z);
    o[i + 3] = __float2bfloat16(v.w);
  }
}

// bias concat: 5 segments of 512 -> bcat[2560]
__global__ void bconcat(const float* b0, const float* b1, const float* b2,
                        const float* b3, const float* b4, float* bcat)
{
  const int d = threadIdx.x;
  const float* src[5] = {b0, b1, b2, b3, b4};
  bcat[blockIdx.x * DD + d] = src[blockIdx.x][d];
}

// ---------------------------------------------------------------------------
// Scans (round-4 structure). proj row m: [omega|gate|mag|g1|qoff] bf16,
// stride NPROJ. phi_init in phib (bf16); running phi fp32 buffer.
// ---------------------------------------------------------------------------
__global__ __launch_bounds__(512) void scan_partialA(
    const bf16* __restrict__ proj, const float* __restrict__ iscale,
    float* __restrict__ pA)
{
  const int b = blockIdx.x >> 7;
  const int c = blockIdx.x & (NCH - 1);
  const int d = threadIdx.x;
  const float sc = fabsf(iscale[d]);
  size_t base = (((size_t)b * SS) + (size_t)c * CHS) * NPROJ + d;
  float acc = 0.f;
  for (int s = 0; s < CHS; ++s) {
    size_t idx = base + (size_t)s * NPROJ;
    acc = fmaf(__bfloat162float(proj[idx]) * __bfloat162float(proj[idx + DD]), sc, acc);
  }
  pA[((size_t)b * NCH + c) * DD + d] = acc;
}

__global__ void scan_excl(float* __restrict__ p, int batch)
{
  int t = blockIdx.x * 256 + threadIdx.x;
  if (t >= batch * DD) return;
  int g = t / DD, d = t % DD;
  size_t base = (size_t)g * NCH * DD + d;
  float run = 0.f;
  for (int c = 0; c < NCH; ++c) {
    size_t idx = base + (size_t)c * DD;
    float v = p[idx];
    p[idx] = run;
    run += v;
  }
}

__global__ __launch_bounds__(512) void scan_stageB(
    const bf16* __restrict__ proj, const bf16* __restrict__ xh,
    const bf16* __restrict__ phib, const float* __restrict__ iscale,
    float* __restrict__ phi, const float* __restrict__ pA,
    float* __restrict__ pRIM)
{
  const int b = blockIdx.x >> 7;
  const int c = blockIdx.x & (NCH - 1);
  const int d = threadIdx.x;
  const float sc = fabsf(iscale[d]);
  float accA = pA[((size_t)b * NCH + c) * DD + d];
  float aR = 0.f, aI = 0.f, aM = 0.f;
  const size_t m0 = (size_t)b * SS + (size_t)c * CHS;
  for (int s = 0; s < CHS; ++s) {
    const size_t m = m0 + s;
    const size_t pj = m * NPROJ + d;
    accA = fmaf(__bfloat162float(proj[pj]) * __bfloat162float(proj[pj + DD]), sc, accA);
    float ph = __bfloat162float(phib[m * DD + d]) + accA;
    phi[m * DD + d] = ph;
    float cp, sp;
    __sincosf(ph, &sp, &cp);
    float mg = __bfloat162float(proj[pj + 2 * DD]);
    float wc = mg * __bfloat162float(xh[m * DD + d]);
    aR = fmaf(wc, cp, aR);
    aI = fmaf(wc, sp, aI);
    aM += mg;
  }
  size_t pidx = ((size_t)b * NCH + c) * DD + d;
  const size_t stride = (size_t)BSL * NCH * DD;
  pRIM[pidx] = aR;
  pRIM[pidx + stride] = aI;
  pRIM[pidx + 2 * stride] = aM;
}

__global__ __launch_bounds__(512) void scan_final(
    const bf16* __restrict__ proj, const bf16* __restrict__ xh,
    const float* __restrict__ phi, const float* __restrict__ pRIM,
    const float* __restrict__ ln_g, const float* __restrict__ ln_b,
    bf16* __restrict__ ctxn)
{
  __shared__ float red[16];
  const int b = blockIdx.x >> 7;
  const int c = blockIdx.x & (NCH - 1);
  const int d = threadIdx.x;
  size_t pidx = ((size_t)b * NCH + c) * DD + d;
  const size_t stride = (size_t)BSL * NCH * DD;
  float aR = pRIM[pidx];
  float aI = pRIM[pidx + stride];
  float aM = pRIM[pidx + 2 * stride];
  const float g0 = ln_g[d],        e0 = ln_b[d];
  const float g1 = ln_g[DD + d],   e1 = ln_b[DD + d];
  const float g2 = ln_g[2*DD + d], e2 = ln_b[2*DD + d];
  const float g3 = ln_g[3*DD + d], e3 = ln_b[3*DD + d];
  const int lane = threadIdx.x & 63;
  const int wv = threadIdx.x >> 6;
  const size_t m0 = (size_t)b * SS + (size_t)c * CHS;
  for (int s = 0; s < CHS; ++s) {
    const size_t m = m0 + s;
    const size_t pj = m * NPROJ + d;
    float ph = phi[m * DD + d];
    float xv = __bfloat162float(xh[m * DD + d]);
    float mg = __bfloat162float(proj[pj + 2 * DD]);
    float cp, sp;
    __sincosf(ph, &sp, &cp);
    float wc = mg * xv;
    aR = fmaf(wc, cp, aR);
    aI = fmaf(wc, sp, aI);
    aM += mg;
    float inv = 1.f / sqrtf(aM + 1e-8f);
    float mr = aR * inv, mi = aI * inv;
    float pq = ph + __bfloat162float(proj[pj + 4 * DD]);
    float cq, sq;
    __sincosf(pq, &sq, &cq);
    float rr = fmaf(mr, cq, mi * sq);
    float ri = fmaf(mi, cq, -(mr * sq));
    float v0 = xv * cp, v1 = xv * sp;
    float lsum = (v0 + v1) + (rr + ri);
    float lsq  = fmaf(v0, v0, fmaf(v1, v1, fmaf(rr, rr, ri * ri)));
#pragma unroll
    for (int o = 32; o > 0; o >>= 1) {
      lsum += __shfl_down(lsum, o);
      lsq  += __shfl_down(lsq, o);
    }
    if (lane == 0) { red[wv] = lsum; red[8 + wv] = lsq; }
    __syncthreads();
    float tsum = red[0] + red[1] + red[2] + red[3] + red[4] + red[5] + red[6] + red[7];
    float tsq  = red[8] + red[9] + red[10] + red[11] + red[12] + red[13] + red[14] + red[15];
    __syncthreads();
    const float invN = 1.f / 2048.f;
    float mean = tsum * invN;
    float var  = tsq * invN - mean * mean;
    float rstd = rsqrtf(var + 1e-5f);
    size_t row = m * (4 * DD);
    ctxn[row + d]        = __float2bfloat16(fmaf((v0 - mean) * rstd, g0, e0));
    ctxn[row + DD + d]   = __float2bfloat16(fmaf((v1 - mean) * rstd, g1, e1));
    ctxn[row + 2*DD + d] = __float2bfloat16(fmaf((rr - mean) * rstd, g2, e2));
    ctxn[row + 3*DD + d] = __float2bfloat16(fmaf((ri - mean) * rstd, g3, e3));
  }
}

// ---------------------------------------------------------------------------
extern "C" void kernel_launch(void* const* d_in, const int* in_sizes, int n_in,
                              void* d_out, int out_size, void* d_ws, size_t ws_size,
                              hipStream_t stream)
{
  const float* x       = (const float*)d_in[0];
  const float* W_omega = (const float*)d_in[1];
  const float* b_omega = (const float*)d_in[2];
  const float* W_p1    = (const float*)d_in[3];
  const float* b_p1    = (const float*)d_in[4];
  const float* W_p2    = (const float*)d_in[5];
  const float* b_p2    = (const float*)d_in[6];
  const float* W_gate  = (const float*)d_in[7];
  const float* b_gate  = (const float*)d_in[8];
  const float* iscale  = (const float*)d_in[9];
  const float* W_mag   = (const float*)d_in[10];
  const float* b_mag   = (const float*)d_in[11];
  const float* W_qoff  = (const float*)d_in[12];
  const float* b_qoff  = (const float*)d_in[13];
  const float* ln_g    = (const float*)d_in[14];
  const float* ln_b    = (const float*)d_in[15];
  const float* W_o1    = (const float*)d_in[16];
  const float* b_o1    = (const float*)d_in[17];
  const float* W_o2    = (const float*)d_in[18];
  const float* b_o2    = (const float*)d_in[19];
  float* out = (float*)d_out;

  // Workspace (~119 MB). Es = BSL*SS*DD = 4.19M; Ms = 8192 rows/slice.
  const size_t Es = (size_t)BSL * SS * DD;
  const size_t Ms = (size_t)BSL * SS;
  char* p = (char*)d_ws;
  bf16* proj  = (bf16*)p; p += Ms * NPROJ * 2;            // 41.9 MB
  bf16* phib  = (bf16*)p; p += Es * 2;                    //  8.4 MB
  float* phi  = (float*)p; p += Es * 4;                   // 16.8 MB
  bf16* xh    = (bf16*)p; p += Es * 2;                    //  8.4 MB
  bf16* ctxn  = (bf16*)p; p += 4 * Es * 2;                // 33.5 MB
  float* pA   = (float*)p; p += (size_t)BSL * NCH * DD * 4;
  float* pRIM = (float*)p; p += 3 * (size_t)BSL * NCH * DD * 4;
  float* bcat = (float*)p; p += NPROJ * 4;
  bf16* WTcat = (bf16*)p; p += (size_t)NPROJ * DD * 2;    //  2.6 MB
  bf16* WTp2  = (bf16*)p; p += (size_t)DD * DD * 2;
  bf16* WTo1  = (bf16*)p; p += (size_t)2048 * 1024 * 2;   //  4.2 MB
  bf16* WTo2  = (bf16*)p; p += (size_t)1024 * 512 * 2;
  bf16* hh    = proj;                                     // [8192,1024] overlay

  dim3 tb(256);
  const size_t WD = (size_t)DD * DD;
  wtrans<<<dim3(16, 16), tb, 0, stream>>>(W_omega, WTcat,          DD, DD);
  wtrans<<<dim3(16, 16), tb, 0, stream>>>(W_gate,  WTcat + WD,     DD, DD);
  wtrans<<<dim3(16, 16), tb, 0, stream>>>(W_mag,   WTcat + 2 * WD, DD, DD);
  wtrans<<<dim3(16, 16), tb, 0, stream>>>(W_p1,    WTcat + 3 * WD, DD, DD);
  wtrans<<<dim3(16, 16), tb, 0, stream>>>(W_qoff,  WTcat + 4 * WD, DD, DD);
  wtrans<<<dim3(16, 16), tb, 0, stream>>>(W_p2,    WTp2, DD, DD);
  wtrans<<<dim3(32, 64), tb, 0, stream>>>(W_o1,    WTo1, 4 * DD, 2 * DD);
  wtrans<<<dim3(16, 32), tb, 0, stream>>>(W_o2,    WTo2, 2 * DD, DD);
  bconcat<<<5, DD, 0, stream>>>(b_omega, b_gate, b_mag, b_p1, b_qoff, bcat);

  const dim3 gP(NPROJ / 128, Ms / 128);        // (20,64)
  const dim3 gD(DD / 128, Ms / 128);           // (4,64)
  const dim3 gO1((2 * DD) / 128, Ms / 128);    // (8,64)

  for (int sl = 0; sl < NSL; ++sl) {
    const float* xs = x + sl * Es;
    float* outs = out + sl * Es;
    castbf<<<(int)(Es / 1024), tb, 0, stream>>>(xs, xh, (int)Es);
    // fused projections + p2
    gemm_mfma<<<gP, tb, 0, stream>>>(xh, DD, WTcat, bcat, nullptr, proj, DD, NPROJ, 9, 1);
    gemm_mfma<<<gD, tb, 0, stream>>>(proj + 3 * DD, NPROJ, WTp2, b_p2, nullptr, phib, DD, DD, 0, 1);
    // scans
    scan_partialA<<<BSL * NCH, 512, 0, stream>>>(proj, iscale, pA);
    scan_excl<<<(BSL * DD + 255) / 256, 256, 0, stream>>>(pA, BSL);
    scan_stageB<<<BSL * NCH, 512, 0, stream>>>(proj, xh, phib, iscale, phi, pA, pRIM);
    scan_excl<<<(3 * BSL * DD + 255) / 256, 256, 0, stream>>>(pRIM, 3 * BSL);
    scan_final<<<BSL * NCH, 512, 0, stream>>>(proj, xh, phi, pRIM, ln_g, ln_b, ctxn);
    // output MLP
    gemm_mfma<<<gO1, tb, 0, stream>>>(ctxn, 4 * DD, WTo1, b_o1, nullptr, hh, 4 * DD, 2 * DD, 3, 1);
    gemm_mfma<<<gD, tb, 0, stream>>>(hh, 2 * DD, WTo2, b_o2, xs, outs, 2 * DD, DD, 0, 0);
  }
}